// Round 14
// baseline (251.795 us; speedup 1.0000x reference)
//
#include <hip/hip_runtime.h>
#include <math.h>

#define B_S   2
#define PIX   4096
#define LL    20480
#define NS    16
#define RR    8
#define NCHK  512     // chunks per sequence
#define LC    40      // steps per chunk
#define SUBS  10      // steps per staging sub-chunk
#define NSUB  4       // LC/SUBS
#define NGRP  32      // chunk groups for combine
#define GCH   16      // chunks per group
#define K0CP  52      // chunk PAIRS kept for K=0 (chunks 0..103, l < 4160)

typedef float v2f __attribute__((ext_vector_type(2)));
typedef float v4f __attribute__((ext_vector_type(4)));

__device__ __forceinline__ v2f pk_mul(v2f a, v2f b) {
  v2f d;
  asm("v_pk_mul_f32 %0, %1, %2" : "=v"(d) : "v"(a), "v"(b));
  return d;
}
// a = b*c + a
#define PK_FMA_ACC(a, b, c) asm("v_pk_fma_f32 %0, %1, %2, %0" : "+v"(a) : "v"(b), "v"(c))
// h = h*e + m
#define PK_DECAY(h, e, m) asm("v_pk_fma_f32 %0, %0, %1, %2" : "+v"(h) : "v"(e), "v"(m))

template<int K>
__device__ __forceinline__ int zmapT(int l) {
  if (K == 0) return l;
  if (K == 1) return ((l % 5) << 12) + l / 5;
  if (K == 2) return 20479 - l;
  int lr = 20479 - l;
  return ((lr % 5) << 12) + lr / 5;
}

// ---- affine grid + bilinear grid_sample: per-pixel taps shared across c ----
__global__ __launch_bounds__(256)
void k_warp(const float* __restrict__ x, const float* __restrict__ nam,
            float* __restrict__ warped) {
  __shared__ float wL[4][64];
  __shared__ int   iL[4][64];
  int blk = blockIdx.x;                 // 20480 = 10 bk * 32 ct * 64 pt
  int bk = blk >> 11;
  int rem = blk & 2047;
  int ct = rem >> 6, pt = rem & 63;
  int p0 = pt * 64;
  int t = threadIdx.x;
  int pl = t & 63, cg = t >> 6;
  if (t < 64) {
    int b = bk / 5, k = bk - b * 5;
    const float* th = nam + (size_t)(b * 25 + k) * 6;
    int p = p0 + t;
    float gx = ((p & 63) + 0.5f) * 0.03125f - 1.0f;
    float gy = ((p >> 6) + 0.5f) * 0.03125f - 1.0f;
    float grx = th[0] * gx + th[1] * gy + th[2];
    float gry = th[3] * gx + th[4] * gy + th[5];
    float ix = ((grx + 1.0f) * 64.0f - 1.0f) * 0.5f;
    float iy = ((gry + 1.0f) * 64.0f - 1.0f) * 0.5f;
    float x0 = floorf(ix), y0 = floorf(iy);
    float fx = ix - x0, fy = iy - y0;
    float vx0 = (x0 >= 0.0f && x0 <= 63.0f) ? 1.0f : 0.0f;
    float vx1 = (x0 >= -1.0f && x0 <= 62.0f) ? 1.0f : 0.0f;
    float vy0 = (y0 >= 0.0f && y0 <= 63.0f) ? 1.0f : 0.0f;
    float vy1 = (y0 >= -1.0f && y0 <= 62.0f) ? 1.0f : 0.0f;
    int xi0 = (int)fminf(fmaxf(x0, 0.0f), 63.0f);
    int yi0 = (int)fminf(fmaxf(y0, 0.0f), 63.0f);
    int xi1 = (int)fminf(fmaxf(x0 + 1.0f, 0.0f), 63.0f);
    int yi1 = (int)fminf(fmaxf(y0 + 1.0f, 0.0f), 63.0f);
    wL[0][t] = (1.0f - fx) * (1.0f - fy) * vx0 * vy0;
    wL[1][t] = fx * (1.0f - fy) * vx1 * vy0;
    wL[2][t] = (1.0f - fx) * fy * vx0 * vy1;
    wL[3][t] = fx * fy * vx1 * vy1;
    iL[0][t] = yi0 * 64 + xi0;
    iL[1][t] = yi0 * 64 + xi1;
    iL[2][t] = yi1 * 64 + xi0;
    iL[3][t] = yi1 * 64 + xi1;
  }
  __syncthreads();
  int c = ct * 4 + cg;
  const float* src = x + (size_t)(bk * 128 + c) * PIX;
  float acc = wL[0][pl] * src[iL[0][pl]]
            + wL[1][pl] * src[iL[1][pl]]
            + wL[2][pl] * src[iL[2][pl]]
            + wL[3][pl] * src[iL[3][pl]];
  warped[((size_t)(bk * 128 + c)) * PIX + p0 + pl] = acc;
}

// ---------------- per-pixel similarity -> softmax alpha ----------------
__global__ __launch_bounds__(512)
void k_alpha(const float* __restrict__ warped, const float* __restrict__ nam,
             float* __restrict__ alpha) {
  __shared__ float part[8][64][9];
  int blk = blockIdx.x;            // 128 blocks
  int b = blk >> 6;
  int p0 = (blk & 63) << 6;
  int wv = threadIdx.x >> 6, lane = threadIdx.x & 63;
  int p = p0 + lane;
  const float* wb = warped + (size_t)b * 5 * 128 * PIX + p;
  float dot[5] = {0,0,0,0,0}, ssq[5] = {0,0,0,0,0};
  int c0 = wv * 16;
  for (int c = c0; c < c0 + 16; ++c) {
    float w0 = wb[(size_t)c * PIX];
    ssq[0] += w0 * w0;
    #pragma unroll
    for (int k = 1; k < 5; ++k) {
      float wk = wb[((size_t)k * 128 + c) * PIX];
      dot[k] += w0 * wk;
      ssq[k] += wk * wk;
    }
  }
  part[wv][lane][0] = ssq[0];
  #pragma unroll
  for (int k = 1; k < 5; ++k) {
    part[wv][lane][k] = dot[k];
    part[wv][lane][4 + k] = ssq[k];
  }
  __syncthreads();
  if (threadIdx.x < 64) {
    float q[9];
    #pragma unroll
    for (int j = 0; j < 9; ++j) {
      float s = 0.0f;
      #pragma unroll
      for (int w = 0; w < 8; ++w) s += part[w][lane][j];
      q[j] = s;
    }
    float n0 = fmaxf(sqrtf(q[0]), 1e-6f);
    float logit[5];
    #pragma unroll
    for (int k = 0; k < 5; ++k) {
      float dotk = (k == 0) ? q[0] : q[k];
      float ssqk = (k == 0) ? q[0] : q[4 + k];
      float nk = fmaxf(sqrtf(ssqk), 1e-6f);
      float sim = fminf(fmaxf(dotk / (n0 * nk), -1.0f), 1.0f);
      float r = fmaxf(1.0f - sim, 0.0f);
      float xr = r * (1.0f / 0.3f);
      float tt = fmaxf(1.0f - xr * xr, 0.0f);
      float wp = fmaxf(tt * tt, 1e-6f);
      const float* th = nam + (size_t)(b * 25 + k) * 6;
      float tx = th[2], ty = th[5];
      float yaw = fabsf(atan2f(th[1], th[0]));
      float gk = 1.0f / (1.0f + __expf(-(2.0f - 0.4f * sqrtf(tx*tx + ty*ty) - 0.8f * yaw)));
      logit[k] = __logf(wp + 1e-8f) + __logf(gk + 1e-8f);
    }
    float m = logit[0];
    #pragma unroll
    for (int k = 1; k < 5; ++k) m = fmaxf(m, logit[k]);
    float e[5], s = 0.0f;
    #pragma unroll
    for (int k = 0; k < 5; ++k) { e[k] = __expf(logit[k] - m); s += e[k]; }
    float inv = 1.0f / s;
    #pragma unroll
    for (int k = 0; k < 5; ++k)
      alpha[((size_t)(b * 5 + k)) * PIX + p] = e[k] * inv;
  }
}

// ---- in_proj GEMM fused with tokens transpose, 2 rows/thread ----
__global__ __launch_bounds__(256, 4)
void k_gemm_in(const float* __restrict__ warped, const float* __restrict__ alpha,
               const float* __restrict__ W, float* __restrict__ X0) {
  __shared__ float xl[64][129];
  __shared__ __align__(16) float wlT[32][132];
  int t = threadIdx.x;
  int row0 = blockIdx.x * 64;             // 640 blocks, rows = b*LL + a*4096 + p
  int b = row0 / LL;
  int z0 = row0 - b * LL;
  int a = z0 >> 12;
  int p0 = z0 & 4095;
  int ba = b * 5 + a;
  int r = t & 63, cg = t >> 6;
  float av = alpha[(size_t)ba * PIX + p0 + r];
  #pragma unroll
  for (int i = 0; i < 32; ++i) {
    int c = cg * 32 + i;
    xl[r][c] = warped[((size_t)ba * 128 + c) * PIX + p0 + r] * av;
  }
  int zl2 = t & 31;          // rows 2*zl2, 2*zl2+1
  int mg  = t >> 5;          // 0..7, cols mg*16..+16
  float acc0[16], acc1[16];
  #pragma unroll
  for (int i = 0; i < 16; ++i) { acc0[i] = 0.0f; acc1[i] = 0.0f; }
  for (int c0 = 0; c0 < 128; c0 += 32) {
    __syncthreads();
    #pragma unroll
    for (int i = 0; i < 16; ++i) {
      int m = (t >> 5) * 16 + i;
      wlT[t & 31][m] = W[(size_t)m * 128 + c0 + (t & 31)];
    }
    __syncthreads();
    const float* xr0 = xl[2 * zl2];
    const float* xr1 = xl[2 * zl2 + 1];
    for (int cc = 0; cc < 32; ++cc) {
      float xv0 = xr0[c0 + cc];
      float xv1 = xr1[c0 + cc];
      const float4* wr = (const float4*)(&wlT[cc][mg * 16]);
      #pragma unroll
      for (int q = 0; q < 4; ++q) {
        float4 w4 = wr[q];
        acc0[q*4+0] = fmaf(w4.x, xv0, acc0[q*4+0]);
        acc0[q*4+1] = fmaf(w4.y, xv0, acc0[q*4+1]);
        acc0[q*4+2] = fmaf(w4.z, xv0, acc0[q*4+2]);
        acc0[q*4+3] = fmaf(w4.w, xv0, acc0[q*4+3]);
        acc1[q*4+0] = fmaf(w4.x, xv1, acc1[q*4+0]);
        acc1[q*4+1] = fmaf(w4.y, xv1, acc1[q*4+1]);
        acc1[q*4+2] = fmaf(w4.z, xv1, acc1[q*4+2]);
        acc1[q*4+3] = fmaf(w4.w, xv1, acc1[q*4+3]);
      }
    }
  }
  __syncthreads();
  #pragma unroll
  for (int q = 0; q < 16; ++q) {
    xl[2 * zl2][mg * 16 + q] = acc0[q];
    xl[2 * zl2 + 1][mg * 16 + q] = acc1[q];
  }
  __syncthreads();
  #pragma unroll
  for (int i = 0; i < 32; ++i) {
    int idx = i * 256 + t;
    X0[((size_t)row0 + (idx >> 7)) * 128 + (idx & 127)] = xl[idx >> 7][idx & 127];
  }
}

// ------- depthwise 3x3 conv over (a=5, p=4096) + SiLU, 4 outputs/thread -------
__global__ __launch_bounds__(256)
void k_conv(const float* __restrict__ X0, const float* __restrict__ cw,
            const float* __restrict__ cb, float* __restrict__ XT) {
  int g = blockIdx.x * 256 + threadIdx.x;   // B*LL*128/4 = 1,310,720
  int d = g & 127;
  int zz4 = g >> 7;                          // (b*LL + z0)/4
  int b = zz4 / (LL / 4);
  int r = zz4 - b * (LL / 4);
  int z0 = r * 4;
  int a = z0 >> 12, p = z0 & 4095;
  float w9[9];
  #pragma unroll
  for (int i = 0; i < 9; ++i) w9[i] = cw[d * 9 + i];
  float cbv = cb[d];
  float acc[4] = {cbv, cbv, cbv, cbv};
  #pragma unroll
  for (int di = 0; di < 3; ++di) {
    int aa = a + di - 1;
    if (aa < 0 || aa >= 5) continue;
    const float* rowb = X0 + ((size_t)b * LL + (size_t)aa * PIX) * 128 + d;
    #pragma unroll
    for (int dj = -1; dj <= 4; ++dj) {
      int pp = p + dj;
      if (pp < 0 || pp >= PIX) continue;
      float v = rowb[(size_t)pp * 128];
      #pragma unroll
      for (int o = 0; o < 4; ++o) {
        int rel = dj - o;
        if (rel >= -1 && rel <= 1) acc[o] = fmaf(w9[di * 3 + rel + 1], v, acc[o]);
      }
    }
  }
  float* dst = XT + (size_t)(zz4 * 4) * 128 + d;
  #pragma unroll
  for (int o = 0; o < 4; ++o) {
    float sg = 1.0f / (1.0f + __expf(-acc[o]));
    dst[(size_t)o * 128] = acc[o] * sg;
  }
}

// ---- x_proj GEMM (2 rows/thread), output permuted to scan order ----
__global__ __launch_bounds__(256, 4)
void k_gemmZ(const float* __restrict__ X, const float* __restrict__ W,
             float* __restrict__ ZdtB, float* __restrict__ ZC) {
  __shared__ float xl[64][129];
  __shared__ __align__(16) float wlT[32][164];
  int t = threadIdx.x;
  int row0 = blockIdx.x * 64;
  #pragma unroll
  for (int i = 0; i < 32; ++i) {
    int idx = i * 256 + t;
    xl[idx >> 7][idx & 127] = X[((size_t)row0 + (idx >> 7)) * 128 + (idx & 127)];
  }
  int zl2 = t & 31;          // rows 2*zl2, 2*zl2+1
  int mg  = t >> 5;          // 0..7: dir = mg>>1, col half = mg&1 (20 cols)
  float acc0[20], acc1[20];
  #pragma unroll
  for (int i = 0; i < 20; ++i) { acc0[i] = 0.0f; acc1[i] = 0.0f; }
  for (int c0 = 0; c0 < 128; c0 += 32) {
    __syncthreads();
    #pragma unroll
    for (int i = 0; i < 20; ++i) {
      int m = (t >> 5) * 20 + i;
      wlT[t & 31][m] = W[(size_t)m * 128 + c0 + (t & 31)];
    }
    __syncthreads();
    const float* xr0 = xl[2 * zl2];
    const float* xr1 = xl[2 * zl2 + 1];
    for (int cc = 0; cc < 32; ++cc) {
      float xv0 = xr0[c0 + cc];
      float xv1 = xr1[c0 + cc];
      const float4* wr = (const float4*)(&wlT[cc][mg * 20]);
      #pragma unroll
      for (int q = 0; q < 5; ++q) {
        float4 w4 = wr[q];
        acc0[q*4+0] = fmaf(w4.x, xv0, acc0[q*4+0]);
        acc0[q*4+1] = fmaf(w4.y, xv0, acc0[q*4+1]);
        acc0[q*4+2] = fmaf(w4.z, xv0, acc0[q*4+2]);
        acc0[q*4+3] = fmaf(w4.w, xv0, acc0[q*4+3]);
        acc1[q*4+0] = fmaf(w4.x, xv1, acc1[q*4+0]);
        acc1[q*4+1] = fmaf(w4.y, xv1, acc1[q*4+1]);
        acc1[q*4+2] = fmaf(w4.z, xv1, acc1[q*4+2]);
        acc1[q*4+3] = fmaf(w4.w, xv1, acc1[q*4+3]);
      }
    }
  }
  int dir = mg >> 1;
  int halfc = mg & 1;
  #pragma unroll
  for (int rr = 0; rr < 2; ++rr) {
    const float* acc = rr ? acc1 : acc0;
    int row = row0 + 2 * zl2 + rr;
    int b = row / LL, z = row - b * LL;
    int a = z >> 12, qq = z & 4095;
    int l;
    if (dir == 0)      l = z;
    else if (dir == 1) l = 5 * qq + a;
    else if (dir == 2) l = 20479 - z;
    else               l = 20479 - (5 * qq + a);
    size_t seqrow = (size_t)(b * 4 + dir) * LL + l;
    if (halfc == 0) {
      float* dD = ZdtB + seqrow * 24;
      #pragma unroll
      for (int q2 = 0; q2 < 5; ++q2)
        *(float4*)(dD + q2 * 4) = make_float4(acc[q2*4], acc[q2*4+1], acc[q2*4+2], acc[q2*4+3]);
    } else {
      float* dD = ZdtB + seqrow * 24;
      *(float4*)(dD + 20) = make_float4(acc[0], acc[1], acc[2], acc[3]);
      float* dC = ZC + seqrow * 16;
      #pragma unroll
      for (int q2 = 0; q2 < 4; ++q2)
        *(float4*)(dC + q2 * 4) = make_float4(acc[4+q2*4], acc[4+q2*4+1], acc[4+q2*4+2], acc[4+q2*4+3]);
    }
  }
}

// ------- single-pass chunked selective scan, 2 chunks per wave (ILP=2) -------
// One step of one chunk: H = h array name, all indices compile-time.
#define STEP1(H, SDT, QRUN, STD, STC, XV, ZVAL, DOY, CIDX)                    \
  {                                                                           \
    const v4f* rowD4_ = (const v4f*)((STD) + s * 24);                         \
    v4f rA_ = rowD4_[0], rB_ = rowD4_[1];                                     \
    float dtl_ = dtb;                                                         \
    dtl_ = fmaf(dw[0], rA_[0], dtl_); dtl_ = fmaf(dw[1], rA_[1], dtl_);       \
    dtl_ = fmaf(dw[2], rA_[2], dtl_); dtl_ = fmaf(dw[3], rA_[3], dtl_);       \
    dtl_ = fmaf(dw[4], rB_[0], dtl_); dtl_ = fmaf(dw[5], rB_[1], dtl_);       \
    dtl_ = fmaf(dw[6], rB_[2], dtl_); dtl_ = fmaf(dw[7], rB_[3], dtl_);       \
    float edt_ = __expf(dtl_);                                                \
    float e1_ = __builtin_amdgcn_rcpf(1.0f + edt_);                           \
    float dt_ = (dtl_ > 20.0f) ? dtl_ : __logf(1.0f + edt_);                  \
    SDT += dt_; QRUN *= e1_;                                                  \
    float dtx_ = dt_ * (XV);                                                  \
    v2f dtx2_ = {dtx_, dtx_};                                                 \
    float e2_ = e1_ * e1_;                                                    \
    v2f E0_ = (v2f){e1_, e2_};                                                \
    v2f e2s_ = {e2_, e2_};                                                    \
    v2f E1_ = pk_mul(E0_, e2s_);                                              \
    v2f E2_ = pk_mul(E1_, e2s_);                                              \
    v2f E3_ = pk_mul(E2_, e2s_);                                              \
    float e8_ = E3_[1];                                                       \
    v2f e8s_ = {e8_, e8_};                                                    \
    v2f E4_ = pk_mul(E0_, e8s_);                                              \
    v2f E5_ = pk_mul(E1_, e8s_);                                              \
    v2f E6_ = pk_mul(E2_, e8s_);                                              \
    v2f E7_ = pk_mul(E3_, e8s_);                                              \
    v4f B0_ = rowD4_[2], B1_ = rowD4_[3], B2_ = rowD4_[4], B3_ = rowD4_[5];   \
    v2f m_;                                                                   \
    m_ = pk_mul(dtx2_, (v2f){B0_[0], B0_[1]});  PK_DECAY(H[0], E0_, m_);      \
    m_ = pk_mul(dtx2_, (v2f){B0_[2], B0_[3]});  PK_DECAY(H[1], E1_, m_);      \
    m_ = pk_mul(dtx2_, (v2f){B1_[0], B1_[1]});  PK_DECAY(H[2], E2_, m_);      \
    m_ = pk_mul(dtx2_, (v2f){B1_[2], B1_[3]});  PK_DECAY(H[3], E3_, m_);      \
    m_ = pk_mul(dtx2_, (v2f){B2_[0], B2_[1]});  PK_DECAY(H[4], E4_, m_);      \
    m_ = pk_mul(dtx2_, (v2f){B2_[2], B2_[3]});  PK_DECAY(H[5], E5_, m_);      \
    m_ = pk_mul(dtx2_, (v2f){B3_[0], B3_[1]});  PK_DECAY(H[6], E6_, m_);      \
    m_ = pk_mul(dtx2_, (v2f){B3_[2], B3_[3]});  PK_DECAY(H[7], E7_, m_);      \
    if (DOY) {                                                                \
      const v4f* C4_ = (const v4f*)((STC) + (CIDX) * 16);                     \
      v4f C0_ = C4_[0], C1_ = C4_[1], C2_ = C4_[2], C3_ = C4_[3];             \
      v2f ya_ = pk_mul(H[0], (v2f){C0_[0], C0_[1]});                          \
      PK_FMA_ACC(ya_, H[1], ((v2f){C0_[2], C0_[3]}));                         \
      PK_FMA_ACC(ya_, H[2], ((v2f){C1_[0], C1_[1]}));                         \
      PK_FMA_ACC(ya_, H[3], ((v2f){C1_[2], C1_[3]}));                         \
      PK_FMA_ACC(ya_, H[4], ((v2f){C2_[0], C2_[1]}));                         \
      PK_FMA_ACC(ya_, H[5], ((v2f){C2_[2], C2_[3]}));                         \
      PK_FMA_ACC(ya_, H[6], ((v2f){C3_[0], C3_[1]}));                         \
      PK_FMA_ACC(ya_, H[7], ((v2f){C3_[2], C3_[3]}));                         \
      float y_ = fmaf(dsv, (XV), ya_[0] + ya_[1]);                            \
      size_t o_ = (size_t)(ZVAL) * 128 + d;                                   \
      ysb[o_] = y_; cqb[o_] = QRUN;                                           \
    }                                                                         \
  }

template<int K>
__device__ void scan_body(int b, int c0, int dh, int lane,
    const float* __restrict__ XT, const float* __restrict__ ZdtB,
    const float* __restrict__ ZC,
    const float* __restrict__ dt_w, const float* __restrict__ dt_b,
    const float* __restrict__ A_logs, const float* __restrict__ Ds,
    const int* __restrict__ chainflags,
    float* __restrict__ h_out, float* __restrict__ sumdts,
    float* __restrict__ ysz, float* __restrict__ cumqv,
    float* stDA, float* stDB, float* stCA, float* stCB)
{
  const int d = dh * 64 + lane;
  const int kd = K * 128 + d;
  bool chainok = chainflags[kd] != 0;
  float dw[8];
  #pragma unroll
  for (int r = 0; r < 8; ++r) dw[r] = dt_w[(size_t)kd * 8 + r];
  const float dtb = dt_b[kd], dsv = Ds[kd];
  v2f h2a[8], h2b[8];
  #pragma unroll
  for (int n = 0; n < 8; ++n) { h2a[n] = (v2f){0.0f, 0.0f}; h2b[n] = (v2f){0.0f, 0.0f}; }
  float sdtA = 0.0f, sdtB = 0.0f, qA = 1.0f, qB = 1.0f;
  const int seq = b * 4 + K;
  const float* ZDs = ZdtB + (size_t)seq * LL * 24;
  const float* ZCs = ZC + (size_t)seq * LL * 16;
  const float* Xb = XT + (size_t)b * LL * 128;
  float* ysb = ysz + (size_t)seq * PIX * 128;
  float* cqb = cumqv + (size_t)seq * PIX * 128;
  const int lA0 = c0 * LC;

  if (__all(chainok ? 1 : 0)) {
    #pragma unroll 1
    for (int sub = 0; sub < NSUB; ++sub) {
      const int lsA = lA0 + sub * SUBS;
      const int lsB = lsA + LC;
      // stage dt/B rows for both chunks (60 float4 each)
      {
        const v4f* sA = (const v4f*)(ZDs + (size_t)lsA * 24);
        const v4f* sB = (const v4f*)(ZDs + (size_t)lsB * 24);
        if (lane < SUBS * 6) {
          ((v4f*)stDA)[lane] = sA[lane];
          ((v4f*)stDB)[lane] = sB[lane];
        }
      }
      int s0cA = 0, s0cB = 0;
      if (K == 1) { s0cA = (5 - (lsA % 5)) % 5; s0cB = (5 - (lsB % 5)) % 5; }
      if (K == 3) { s0cA = (9 - (lsA % 5)) % 5; s0cB = (9 - (lsB % 5)) % 5; }
      if (K == 0 || K == 2) {
        bool nCA = (K == 0) ? (lsA < PIX) : (lsA + SUBS > LL - PIX);
        bool nCB = (K == 0) ? (lsB < PIX) : (lsB + SUBS > LL - PIX);
        if (nCA && lane < SUBS * 4)
          ((v4f*)stCA)[lane] = ((const v4f*)(ZCs + (size_t)lsA * 16))[lane];
        if (nCB && lane < SUBS * 4)
          ((v4f*)stCB)[lane] = ((const v4f*)(ZCs + (size_t)lsB * 16))[lane];
      } else {
        if (lane < 8) {
          int l = lsA + s0cA + 5 * (lane >> 2);
          if (l > LL - 1) l = LL - 1;
          ((v4f*)stCA)[lane] = *(const v4f*)(ZCs + (size_t)l * 16 + (lane & 3) * 4);
        } else if (lane < 16) {
          int ll = lane - 8;
          int l = lsB + s0cB + 5 * (ll >> 2);
          if (l > LL - 1) l = LL - 1;
          ((v4f*)stCB)[ll] = *(const v4f*)(ZCs + (size_t)l * 16 + (ll & 3) * 4);
        }
      }
      // register-stage x for both chunks
      float xrA[SUBS], xrB[SUBS];
      #pragma unroll
      for (int s = 0; s < SUBS; ++s) {
        xrA[s] = Xb[(size_t)zmapT<K>(lsA + s) * 128 + d];
        xrB[s] = Xb[(size_t)zmapT<K>(lsB + s) * 128 + d];
      }
      int zcA = 0, zcB = 0;
      if (K == 1) { zcA = (lsA + s0cA) / 5; zcB = (lsB + s0cB) / 5; }
      if (K == 3) { zcA = (20479 - lsA - s0cA) / 5; zcB = (20479 - lsB - s0cB) / 5; }
      int yjA = 0, yjB = 0;
      #pragma unroll
      for (int s = 0; s < SUBS; ++s) {
        bool doYA; int zA;
        if (K == 0)      { zA = lsA + s;            doYA = (zA < PIX); }
        else if (K == 2) { zA = 20479 - (lsA + s);  doYA = (zA < PIX); }
        else             { zA = zcA;                doYA = ((s % 5) == s0cA); }
        int ciA = (K == 0 || K == 2) ? s : yjA;
        STEP1(h2a, sdtA, qA, stDA, stCA, xrA[s], zA, doYA, ciA);
        if (doYA) { ++yjA; if (K == 1) ++zcA; if (K == 3) --zcA; }
        bool doYB; int zB;
        if (K == 0)      { zB = lsB + s;            doYB = (zB < PIX); }
        else if (K == 2) { zB = 20479 - (lsB + s);  doYB = (zB < PIX); }
        else             { zB = zcB;                doYB = ((s % 5) == s0cB); }
        int ciB = (K == 0 || K == 2) ? s : yjB;
        STEP1(h2b, sdtB, qB, stDB, stCB, xrB[s], zB, doYB, ciB);
        if (doYB) { ++yjB; if (K == 1) ++zcB; if (K == 3) --zcB; }
      }
    }
  } else {
    // general fallback (compact, never taken for this A_logs)
    float An[NS];
    #pragma unroll
    for (int n = 0; n < NS; ++n) An[n] = -__expf(A_logs[(size_t)kd * 16 + n]);
    #pragma unroll 1
    for (int half = 0; half < 2; ++half) {
      float hs[NS];
      #pragma unroll
      for (int n = 0; n < NS; ++n) hs[n] = 0.0f;
      float sdt = 0.0f;
      int l0 = (c0 + half) * LC;
      #pragma unroll 1
      for (int l = l0; l < l0 + LC; ++l) {
        int z = zmapT<K>(l);
        const float* rowD = ZDs + (size_t)l * 24;
        float dtl = dtb;
        #pragma unroll
        for (int r = 0; r < RR; ++r) dtl += dw[r] * rowD[r];
        float edt = __expf(dtl);
        float dt = (dtl > 20.0f) ? dtl : __logf(1.0f + edt);
        sdt += dt;
        float xv = Xb[(size_t)z * 128 + d];
        float dtx = dt * xv;
        #pragma unroll
        for (int n = 0; n < NS; ++n)
          hs[n] = hs[n] * __expf(dt * An[n]) + dtx * rowD[8 + n];
        if (z < PIX) {
          const float* rowC = ZCs + (size_t)l * 16;
          float y = dsv * xv;
          #pragma unroll
          for (int n = 0; n < NS; ++n) y = fmaf(hs[n], rowC[n], y);
          size_t o = (size_t)z * 128 + d;
          ysb[o] = y;
          cqb[o] = __expf(-sdt);
        }
      }
      if (half == 0) {
        sdtA = sdt;
        #pragma unroll
        for (int n = 0; n < 8; ++n) h2a[n] = (v2f){hs[2*n], hs[2*n+1]};
      } else {
        sdtB = sdt;
        #pragma unroll
        for (int n = 0; n < 8; ++n) h2b[n] = (v2f){hs[2*n], hs[2*n+1]};
      }
    }
  }
  float* hoA = h_out + (((size_t)seq * NCHK + c0) * 128 + d) * 16;
  float* hoB = h_out + (((size_t)seq * NCHK + c0 + 1) * 128 + d) * 16;
  #pragma unroll
  for (int n = 0; n < 8; ++n) {
    hoA[2*n] = h2a[n][0]; hoA[2*n+1] = h2a[n][1];
    hoB[2*n] = h2b[n][0]; hoB[2*n+1] = h2b[n][1];
  }
  sumdts[((size_t)seq * NCHK + c0) * 128 + d] = sdtA;
  sumdts[((size_t)seq * NCHK + c0 + 1) * 128 + d] = sdtB;
}

__global__ __launch_bounds__(128, 4)
void k_scan1(const float* __restrict__ XT, const float* __restrict__ ZdtB,
             const float* __restrict__ ZC,
             const float* __restrict__ dt_w, const float* __restrict__ dt_b,
             const float* __restrict__ A_logs, const float* __restrict__ Ds,
             const int* __restrict__ chainflags,
             float* __restrict__ h_out, float* __restrict__ sumdts,
             float* __restrict__ ysz, float* __restrict__ cumqv) {
  __shared__ __align__(16) float stD_all[2][2][SUBS * 24];
  __shared__ __align__(16) float stC_all[2][2][SUBS * 16];
  int tid = threadIdx.x, wid = tid >> 6, lane = tid & 63;
  int bid = blockIdx.x;            // B * (K0CP + 3*256) = 1640
  int bb = bid / (K0CP + 768);
  int idx = bid - bb * (K0CP + 768);
  int k, cpair;
  if (idx < K0CP)            { k = 0; cpair = idx; }
  else if (idx < K0CP + 256) { k = 1; cpair = idx - K0CP; }
  else if (idx < K0CP + 512) { k = 2; cpair = idx - (K0CP + 256); }
  else                       { k = 3; cpair = idx - (K0CP + 512); }
  int c0 = cpair * 2;
  int dh = wid;
  float* stDA = stD_all[wid][0];
  float* stDB = stD_all[wid][1];
  float* stCA = stC_all[wid][0];
  float* stCB = stC_all[wid][1];
  switch (k) {
    case 0: scan_body<0>(bb, c0, dh, lane, XT, ZdtB, ZC, dt_w, dt_b, A_logs, Ds, chainflags, h_out, sumdts, ysz, cumqv, stDA, stDB, stCA, stCB); break;
    case 1: scan_body<1>(bb, c0, dh, lane, XT, ZdtB, ZC, dt_w, dt_b, A_logs, Ds, chainflags, h_out, sumdts, ysz, cumqv, stDA, stDB, stCA, stCB); break;
    case 2: scan_body<2>(bb, c0, dh, lane, XT, ZdtB, ZC, dt_w, dt_b, A_logs, Ds, chainflags, h_out, sumdts, ysz, cumqv, stDA, stDB, stCA, stCB); break;
    default: scan_body<3>(bb, c0, dh, lane, XT, ZdtB, ZC, dt_w, dt_b, A_logs, Ds, chainflags, h_out, sumdts, ysz, cumqv, stDA, stDB, stCA, stCB); break;
  }
}

// ---- combine level A: per-group affine fold (Ag = prod a, Bg = fold b) ----
// k=0 only needs groups 0..6 (output chunks <=102).
__global__ __launch_bounds__(256)
void k_comb_a(const float* __restrict__ A_logs, const float* __restrict__ sumdts,
              const float* __restrict__ h_out, float* __restrict__ Ag,
              float* __restrict__ Bg) {
  int g = blockIdx.x * 256 + threadIdx.x;   // 8*32*128*16 = 524288
  int n = g & 15;
  int d = (g >> 4) & 127;
  int grp = (g >> 11) & 31;
  int seq = g >> 16;
  int k = seq & 3;
  if (k == 0 && grp > 6) return;            // unused by prefix/replay
  float An = -__expf(A_logs[(size_t)(k * 128 + d) * 16 + n]);
  float A = 1.0f, Bv = 0.0f;
  size_t cbase = (size_t)seq * NCHK + grp * GCH;
  #pragma unroll 4
  for (int j = 0; j < GCH; ++j) {
    float a = __expf(An * sumdts[(cbase + j) * 128 + d]);
    float b = h_out[((cbase + j) * 128 + d) * 16 + n];
    A *= a;
    Bv = Bv * a + b;
  }
  size_t o = (((size_t)seq * NGRP + grp) * 128 + d) * 16 + n;
  Ag[o] = A;
  Bg[o] = Bv;
}

// ---- combine level B: prefix over 32 groups ----
__global__ __launch_bounds__(256)
void k_comb_b(const float* __restrict__ Ag, const float* __restrict__ Bg,
              float* __restrict__ Hg) {
  int g = blockIdx.x * 256 + threadIdx.x;   // 8*128*16 = 16384
  int n = g & 15;
  int d = (g >> 4) & 127;
  int seq = g >> 11;
  float H = 0.0f;
  #pragma unroll
  for (int grp = 0; grp < NGRP; ++grp) {
    size_t o = (((size_t)seq * NGRP + grp) * 128 + d) * 16 + n;
    Hg[o] = H;
    H = Ag[o] * H + Bg[o];
  }
}

// ---- combine level C: replay within group -> h_in per chunk ----
// k=0 needs groups 0..6 only; k=2 replay needs groups 25..31 only.
__global__ __launch_bounds__(256)
void k_comb_c(const float* __restrict__ A_logs, const float* __restrict__ sumdts,
              const float* __restrict__ h_out, const float* __restrict__ Hg,
              float* __restrict__ h_in) {
  int g = blockIdx.x * 256 + threadIdx.x;   // 524288
  int n = g & 15;
  int d = (g >> 4) & 127;
  int grp = (g >> 11) & 31;
  int seq = g >> 16;
  int k = seq & 3;
  if (k == 0 && grp > 6) return;
  if (k == 2 && grp < 25) return;
  float An = -__expf(A_logs[(size_t)(k * 128 + d) * 16 + n]);
  float h = Hg[(((size_t)seq * NGRP + grp) * 128 + d) * 16 + n];
  size_t cbase = (size_t)seq * NCHK + grp * GCH;
  #pragma unroll 4
  for (int j = 0; j < GCH; ++j) {
    size_t o = ((cbase + j) * 128 + d) * 16 + n;
    h_in[o] = h;
    float a = __expf(An * sumdts[(cbase + j) * 128 + d]);
    h = a * h + h_out[o];
  }
}

// ------- transpose out_proj_w + precompute per-kd chain flags -------
__global__ __launch_bounds__(256)
void k_wt(const float* __restrict__ Wo, float* __restrict__ WT,
          const float* __restrict__ A_logs, int* __restrict__ chainflags) {
  if (blockIdx.x >= 16) {
    int kd = (blockIdx.x - 16) * 256 + threadIdx.x;   // 0..511
    bool c = true;
    #pragma unroll
    for (int n = 0; n < NS; ++n) {
      float An = -__expf(A_logs[(size_t)kd * 16 + n]);
      c = c && (fabsf(An + (float)(n + 1)) < 3e-5f * (float)(n + 1));
    }
    chainflags[kd] = c ? 1 : 0;
    return;
  }
  __shared__ float tl[32][33];
  int bx = blockIdx.x & 3, by = blockIdx.x >> 2;
  int t = threadIdx.x;
  int tx = t & 31, ty = t >> 5;
  #pragma unroll
  for (int i = 0; i < 4; ++i)
    tl[ty + i * 8][tx] = Wo[(size_t)(by * 32 + ty + i * 8) * 128 + bx * 32 + tx];
  __syncthreads();
  #pragma unroll
  for (int i = 0; i < 4; ++i)
    WT[(size_t)(bx * 32 + ty + i * 8) * 128 + by * 32 + tx] = tl[tx][ty + i * 8];
}

// ------- merge 4 dirs + cross-chunk fix + LayerNorm + out_proj -------
__global__ __launch_bounds__(256)
void k_merge(const float* __restrict__ ysz, const float* __restrict__ ZC,
             const float* __restrict__ A_logs, const float* __restrict__ h_in,
             const float* __restrict__ cumq, const int* __restrict__ chainflags,
             const float* __restrict__ ln_g, const float* __restrict__ ln_b,
             const float* __restrict__ WT, float* __restrict__ out) {
  __shared__ __align__(16) float ynT[128][20];
  __shared__ float red[4][8][2];
  int blk = blockIdx.x;          // 512: b = blk>>8, ptile = blk&255
  int b = blk >> 8;
  int p0 = (blk & 255) * 16;
  int tid = threadIdx.x;
  int t = tid & 127;             // channel d
  int half = tid >> 7;           // 0/1
  int w = tid >> 6;              // wave 0..3
  float g = ln_g[t], bb = ln_b[t];
  bool cok[4];
  #pragma unroll
  for (int k = 0; k < 4; ++k) cok[k] = chainflags[k * 128 + t] != 0;
  float yv[8];
  #pragma unroll
  for (int i = 0; i < 8; ++i) {
    int p = p0 + 2 * i + half;
    float y = 0.0f;
    #pragma unroll
    for (int k = 0; k < 4; ++k) {
      size_t zi = ((size_t)(b * 4 + k) * PIX + p) * 128 + t;
      float yk = ysz[zi];
      int l;
      if (k == 0)      l = p;
      else if (k == 1) l = 5 * p;
      else if (k == 2) l = 20479 - p;
      else             l = 20479 - 5 * p;
      int chunk = l / LC;
      float q = cumq[zi];
      const v2f* hi2 = (const v2f*)(h_in + (((size_t)(b * 4 + k) * NCHK + chunk) * 128 + t) * 16);
      const v2f* Cr2 = (const v2f*)(ZC + ((size_t)(b * 4 + k) * LL + l) * 16);
      float fix;
      if (cok[k]) {
        float q2 = q * q;
        v2f Q[8];
        Q[0] = (v2f){q, q2};
        v2f q2s = {q2, q2};
        Q[1] = pk_mul(Q[0], q2s);
        Q[2] = pk_mul(Q[1], q2s);
        Q[3] = pk_mul(Q[2], q2s);
        float q8 = Q[3][1];
        v2f q8s = {q8, q8};
        Q[4] = pk_mul(Q[0], q8s);
        Q[5] = pk_mul(Q[1], q8s);
        Q[6] = pk_mul(Q[2], q8s);
        Q[7] = pk_mul(Q[3], q8s);
        v2f a = pk_mul(pk_mul(hi2[0], Cr2[0]), Q[0]);
        #pragma unroll
        for (int j = 1; j < 8; ++j) {
          v2f m = pk_mul(hi2[j], Cr2[j]);
          PK_FMA_ACC(a, m, Q[j]);
        }
        fix = a[0] + a[1];
      } else {
        float cd = -__logf(q);
        fix = 0.0f;
        const float* hi = (const float*)hi2;
        const float* Cr = (const float*)Cr2;
        #pragma unroll
        for (int n = 0; n < NS; ++n) {
          float An = -__expf(A_logs[(size_t)(k * 128 + t) * 16 + n]);
          fix += Cr[n] * hi[n] * __expf(An * cd);
        }
      }
      y += yk + fix;
    }
    yv[i] = y;
    float s1 = y, s2 = y * y;
    #pragma unroll
    for (int off = 32; off; off >>= 1) {
      s1 += __shfl_xor(s1, off);
      s2 += __shfl_xor(s2, off);
    }
    if ((tid & 63) == 0) { red[w][i][0] = s1; red[w][i][1] = s2; }
  }
  __syncthreads();
  #pragma unroll
  for (int i = 0; i < 8; ++i) {
    int pl = 2 * i + half;
    float S1 = red[half * 2][i][0] + red[half * 2 + 1][i][0];
    float S2 = red[half * 2][i][1] + red[half * 2 + 1][i][1];
    float mu = S1 * (1.0f / 128.0f);
    float var = S2 * (1.0f / 128.0f) - mu * mu;
    float rs = rsqrtf(var + 1e-5f);
    ynT[t][pl] = (yv[i] - mu) * rs * g + bb;
  }
  __syncthreads();
  float acc[8];
  #pragma unroll
  for (int i = 0; i < 8; ++i) acc[i] = 0.0f;
  for (int dd = 0; dd < 128; ++dd) {
    float wv = WT[(size_t)dd * 128 + t];
    const float4* yr = (const float4*)(&ynT[dd][half * 8]);
    float4 ya = yr[0], yb4 = yr[1];
    acc[0] = fmaf(ya.x,  wv, acc[0]);
    acc[1] = fmaf(ya.y,  wv, acc[1]);
    acc[2] = fmaf(ya.z,  wv, acc[2]);
    acc[3] = fmaf(ya.w,  wv, acc[3]);
    acc[4] = fmaf(yb4.x, wv, acc[4]);
    acc[5] = fmaf(yb4.y, wv, acc[5]);
    acc[6] = fmaf(yb4.z, wv, acc[6]);
    acc[7] = fmaf(yb4.w, wv, acc[7]);
  }
  float* dst = out + ((size_t)b * 128 + t) * PIX + p0 + half * 8;
  *(float4*)(dst)     = make_float4(acc[0], acc[1], acc[2], acc[3]);
  *(float4*)(dst + 4) = make_float4(acc[4], acc[5], acc[6], acc[7]);
}

extern "C" void kernel_launch(void* const* d_in, const int* in_sizes, int n_in,
                              void* d_out, int out_size, void* d_ws, size_t ws_size,
                              hipStream_t stream) {
  const float* x         = (const float*)d_in[0];
  // d_in[1] record_len unused
  const float* nam       = (const float*)d_in[2];
  const float* in_proj_w = (const float*)d_in[3];
  const float* conv_w    = (const float*)d_in[4];
  const float* conv_b    = (const float*)d_in[5];
  const float* x_proj_w  = (const float*)d_in[6];
  const float* dt_w      = (const float*)d_in[7];
  const float* dt_b      = (const float*)d_in[8];
  const float* A_logs    = (const float*)d_in[9];
  const float* Ds        = (const float*)d_in[10];
  const float* ln_g      = (const float*)d_in[11];
  const float* ln_b      = (const float*)d_in[12];
  const float* out_proj_w= (const float*)d_in[13];
  float* out = (float*)d_out;
  float* ws  = (float*)d_ws;

  // workspace layout (floats), total ~32.8M (~131 MB)
  float* warped = ws;                          // 5,242,880
  float* alpha  = warped + 5242880;            //    40,960
  float* X0     = alpha  + 40960;              // 5,242,880   (end 10,526,720)
  float* XT     = X0     + 5242880;            // 5,242,880
  float* ZdtB   = XT     + 5242880;            // 3,932,160   (end 19,701,760)
  float* ZC     = ZdtB   + 3932160;            // 2,621,440
  float* sums   = ZC     + 2621440;            //   524,288
  float* ysz    = sums   + 524288;             // 4,194,304
  float* cumq   = ysz    + 4194304;            // 4,194,304
  float* WT     = cumq   + 4194304;            //    16,384
  float* Ag     = WT     + 16384;              //   524,288
  float* Bg     = Ag     + 524288;             //   524,288
  float* Hg     = Bg     + 524288;             //   524,288
  int*   chainflags = (int*)(Hg + 524288);     //       512 ints

  // aliases: h_out (8.39M) over warped+alpha+X0 (dead after k_conv);
  //          h_in  (8.39M) over XT+ZdtB (dead after k_scan1)
  float* h_out = ws;
  float* h_in  = XT;

  k_wt     <<<18,    256, 0, stream>>>(out_proj_w, WT, A_logs, chainflags);
  k_warp   <<<20480, 256, 0, stream>>>(x, nam, warped);
  k_alpha  <<<128,   512, 0, stream>>>(warped, nam, alpha);
  k_gemm_in<<<640,   256, 0, stream>>>(warped, alpha, in_proj_w, X0);
  k_conv   <<<5120,  256, 0, stream>>>(X0, conv_w, conv_b, XT);
  k_gemmZ  <<<640,   256, 0, stream>>>(XT, x_proj_w, ZdtB, ZC);
  k_scan1  <<<B_S * (K0CP + 768), 128, 0, stream>>>(XT, ZdtB, ZC, dt_w, dt_b,
                                                    A_logs, Ds, chainflags,
                                                    h_out, sums, ysz, cumq);
  k_comb_a <<<2048,  256, 0, stream>>>(A_logs, sums, h_out, Ag, Bg);
  k_comb_b <<<64,    256, 0, stream>>>(Ag, Bg, Hg);
  k_comb_c <<<2048,  256, 0, stream>>>(A_logs, sums, h_out, Hg, h_in);
  k_merge  <<<512,   256, 0, stream>>>(ysz, ZC, A_logs, h_in, cumq, chainflags,
                                       ln_g, ln_b, WT, out);
}

// Round 15
// 245.011 us; speedup vs baseline: 1.0277x; 1.0277x over previous
//
#include <hip/hip_runtime.h>
#include <math.h>

#define B_S   2
#define PIX   4096
#define LL    20480
#define NS    16
#define RR    8
#define NCHK  512     // chunks per sequence
#define LC    40      // steps per chunk
#define SUBS  10      // steps per staging sub-chunk
#define NSUB  4       // LC/SUBS
#define NGRP  32      // chunk groups for combine
#define GCH   16      // chunks per group
#define K0CH  104     // chunks kept for K=0 (l < 4160)

typedef float v2f __attribute__((ext_vector_type(2)));
typedef float v4f __attribute__((ext_vector_type(4)));

__device__ __forceinline__ v2f pk_mul(v2f a, v2f b) {
  v2f d;
  asm("v_pk_mul_f32 %0, %1, %2" : "=v"(d) : "v"(a), "v"(b));
  return d;
}
// a = b*c + a
#define PK_FMA_ACC(a, b, c) asm("v_pk_fma_f32 %0, %1, %2, %0" : "+v"(a) : "v"(b), "v"(c))
// h = h*e + m
#define PK_DECAY(h, e, m) asm("v_pk_fma_f32 %0, %0, %1, %2" : "+v"(h) : "v"(e), "v"(m))

template<int K>
__device__ __forceinline__ int zmapT(int l) {
  if (K == 0) return l;
  if (K == 1) return ((l % 5) << 12) + l / 5;
  if (K == 2) return 20479 - l;
  int lr = 20479 - l;
  return ((lr % 5) << 12) + lr / 5;
}

// ---- affine grid + bilinear grid_sample: per-pixel taps shared across c ----
__global__ __launch_bounds__(256)
void k_warp(const float* __restrict__ x, const float* __restrict__ nam,
            float* __restrict__ warped) {
  __shared__ float wL[4][64];
  __shared__ int   iL[4][64];
  int blk = blockIdx.x;                 // 20480 = 10 bk * 32 ct * 64 pt
  int bk = blk >> 11;
  int rem = blk & 2047;
  int ct = rem >> 6, pt = rem & 63;
  int p0 = pt * 64;
  int t = threadIdx.x;
  int pl = t & 63, cg = t >> 6;
  if (t < 64) {
    int b = bk / 5, k = bk - b * 5;
    const float* th = nam + (size_t)(b * 25 + k) * 6;
    int p = p0 + t;
    float gx = ((p & 63) + 0.5f) * 0.03125f - 1.0f;
    float gy = ((p >> 6) + 0.5f) * 0.03125f - 1.0f;
    float grx = th[0] * gx + th[1] * gy + th[2];
    float gry = th[3] * gx + th[4] * gy + th[5];
    float ix = ((grx + 1.0f) * 64.0f - 1.0f) * 0.5f;
    float iy = ((gry + 1.0f) * 64.0f - 1.0f) * 0.5f;
    float x0 = floorf(ix), y0 = floorf(iy);
    float fx = ix - x0, fy = iy - y0;
    float vx0 = (x0 >= 0.0f && x0 <= 63.0f) ? 1.0f : 0.0f;
    float vx1 = (x0 >= -1.0f && x0 <= 62.0f) ? 1.0f : 0.0f;
    float vy0 = (y0 >= 0.0f && y0 <= 63.0f) ? 1.0f : 0.0f;
    float vy1 = (y0 >= -1.0f && y0 <= 62.0f) ? 1.0f : 0.0f;
    int xi0 = (int)fminf(fmaxf(x0, 0.0f), 63.0f);
    int yi0 = (int)fminf(fmaxf(y0, 0.0f), 63.0f);
    int xi1 = (int)fminf(fmaxf(x0 + 1.0f, 0.0f), 63.0f);
    int yi1 = (int)fminf(fmaxf(y0 + 1.0f, 0.0f), 63.0f);
    wL[0][t] = (1.0f - fx) * (1.0f - fy) * vx0 * vy0;
    wL[1][t] = fx * (1.0f - fy) * vx1 * vy0;
    wL[2][t] = (1.0f - fx) * fy * vx0 * vy1;
    wL[3][t] = fx * fy * vx1 * vy1;
    iL[0][t] = yi0 * 64 + xi0;
    iL[1][t] = yi0 * 64 + xi1;
    iL[2][t] = yi1 * 64 + xi0;
    iL[3][t] = yi1 * 64 + xi1;
  }
  __syncthreads();
  int c = ct * 4 + cg;
  const float* src = x + (size_t)(bk * 128 + c) * PIX;
  float acc = wL[0][pl] * src[iL[0][pl]]
            + wL[1][pl] * src[iL[1][pl]]
            + wL[2][pl] * src[iL[2][pl]]
            + wL[3][pl] * src[iL[3][pl]];
  warped[((size_t)(bk * 128 + c)) * PIX + p0 + pl] = acc;
}

// ---------------- per-pixel similarity -> softmax alpha ----------------
__global__ __launch_bounds__(512)
void k_alpha(const float* __restrict__ warped, const float* __restrict__ nam,
             float* __restrict__ alpha) {
  __shared__ float part[8][64][9];
  int blk = blockIdx.x;            // 128 blocks
  int b = blk >> 6;
  int p0 = (blk & 63) << 6;
  int wv = threadIdx.x >> 6, lane = threadIdx.x & 63;
  int p = p0 + lane;
  const float* wb = warped + (size_t)b * 5 * 128 * PIX + p;
  float dot[5] = {0,0,0,0,0}, ssq[5] = {0,0,0,0,0};
  int c0 = wv * 16;
  for (int c = c0; c < c0 + 16; ++c) {
    float w0 = wb[(size_t)c * PIX];
    ssq[0] += w0 * w0;
    #pragma unroll
    for (int k = 1; k < 5; ++k) {
      float wk = wb[((size_t)k * 128 + c) * PIX];
      dot[k] += w0 * wk;
      ssq[k] += wk * wk;
    }
  }
  part[wv][lane][0] = ssq[0];
  #pragma unroll
  for (int k = 1; k < 5; ++k) {
    part[wv][lane][k] = dot[k];
    part[wv][lane][4 + k] = ssq[k];
  }
  __syncthreads();
  if (threadIdx.x < 64) {
    float q[9];
    #pragma unroll
    for (int j = 0; j < 9; ++j) {
      float s = 0.0f;
      #pragma unroll
      for (int w = 0; w < 8; ++w) s += part[w][lane][j];
      q[j] = s;
    }
    float n0 = fmaxf(sqrtf(q[0]), 1e-6f);
    float logit[5];
    #pragma unroll
    for (int k = 0; k < 5; ++k) {
      float dotk = (k == 0) ? q[0] : q[k];
      float ssqk = (k == 0) ? q[0] : q[4 + k];
      float nk = fmaxf(sqrtf(ssqk), 1e-6f);
      float sim = fminf(fmaxf(dotk / (n0 * nk), -1.0f), 1.0f);
      float r = fmaxf(1.0f - sim, 0.0f);
      float xr = r * (1.0f / 0.3f);
      float tt = fmaxf(1.0f - xr * xr, 0.0f);
      float wp = fmaxf(tt * tt, 1e-6f);
      const float* th = nam + (size_t)(b * 25 + k) * 6;
      float tx = th[2], ty = th[5];
      float yaw = fabsf(atan2f(th[1], th[0]));
      float gk = 1.0f / (1.0f + __expf(-(2.0f - 0.4f * sqrtf(tx*tx + ty*ty) - 0.8f * yaw)));
      logit[k] = __logf(wp + 1e-8f) + __logf(gk + 1e-8f);
    }
    float m = logit[0];
    #pragma unroll
    for (int k = 1; k < 5; ++k) m = fmaxf(m, logit[k]);
    float e[5], s = 0.0f;
    #pragma unroll
    for (int k = 0; k < 5; ++k) { e[k] = __expf(logit[k] - m); s += e[k]; }
    float inv = 1.0f / s;
    #pragma unroll
    for (int k = 0; k < 5; ++k)
      alpha[((size_t)(b * 5 + k)) * PIX + p] = e[k] * inv;
  }
}

// ---- in_proj GEMM fused with tokens transpose, 2 rows/thread ----
__global__ __launch_bounds__(256, 4)
void k_gemm_in(const float* __restrict__ warped, const float* __restrict__ alpha,
               const float* __restrict__ W, float* __restrict__ X0) {
  __shared__ float xl[64][129];
  __shared__ __align__(16) float wlT[32][132];
  int t = threadIdx.x;
  int row0 = blockIdx.x * 64;             // 640 blocks, rows = b*LL + a*4096 + p
  int b = row0 / LL;
  int z0 = row0 - b * LL;
  int a = z0 >> 12;
  int p0 = z0 & 4095;
  int ba = b * 5 + a;
  int r = t & 63, cg = t >> 6;
  float av = alpha[(size_t)ba * PIX + p0 + r];
  #pragma unroll
  for (int i = 0; i < 32; ++i) {
    int c = cg * 32 + i;
    xl[r][c] = warped[((size_t)ba * 128 + c) * PIX + p0 + r] * av;
  }
  int zl2 = t & 31;          // rows 2*zl2, 2*zl2+1
  int mg  = t >> 5;          // 0..7, cols mg*16..+16
  float acc0[16], acc1[16];
  #pragma unroll
  for (int i = 0; i < 16; ++i) { acc0[i] = 0.0f; acc1[i] = 0.0f; }
  for (int c0 = 0; c0 < 128; c0 += 32) {
    __syncthreads();
    #pragma unroll
    for (int i = 0; i < 16; ++i) {
      int m = (t >> 5) * 16 + i;
      wlT[t & 31][m] = W[(size_t)m * 128 + c0 + (t & 31)];
    }
    __syncthreads();
    const float* xr0 = xl[2 * zl2];
    const float* xr1 = xl[2 * zl2 + 1];
    for (int cc = 0; cc < 32; ++cc) {
      float xv0 = xr0[c0 + cc];
      float xv1 = xr1[c0 + cc];
      const float4* wr = (const float4*)(&wlT[cc][mg * 16]);
      #pragma unroll
      for (int q = 0; q < 4; ++q) {
        float4 w4 = wr[q];
        acc0[q*4+0] = fmaf(w4.x, xv0, acc0[q*4+0]);
        acc0[q*4+1] = fmaf(w4.y, xv0, acc0[q*4+1]);
        acc0[q*4+2] = fmaf(w4.z, xv0, acc0[q*4+2]);
        acc0[q*4+3] = fmaf(w4.w, xv0, acc0[q*4+3]);
        acc1[q*4+0] = fmaf(w4.x, xv1, acc1[q*4+0]);
        acc1[q*4+1] = fmaf(w4.y, xv1, acc1[q*4+1]);
        acc1[q*4+2] = fmaf(w4.z, xv1, acc1[q*4+2]);
        acc1[q*4+3] = fmaf(w4.w, xv1, acc1[q*4+3]);
      }
    }
  }
  __syncthreads();
  #pragma unroll
  for (int q = 0; q < 16; ++q) {
    xl[2 * zl2][mg * 16 + q] = acc0[q];
    xl[2 * zl2 + 1][mg * 16 + q] = acc1[q];
  }
  __syncthreads();
  #pragma unroll
  for (int i = 0; i < 32; ++i) {
    int idx = i * 256 + t;
    X0[((size_t)row0 + (idx >> 7)) * 128 + (idx & 127)] = xl[idx >> 7][idx & 127];
  }
}

// ------- depthwise 3x3 conv over (a=5, p=4096) + SiLU, 4 outputs/thread -------
__global__ __launch_bounds__(256)
void k_conv(const float* __restrict__ X0, const float* __restrict__ cw,
            const float* __restrict__ cb, float* __restrict__ XT) {
  int g = blockIdx.x * 256 + threadIdx.x;   // B*LL*128/4 = 1,310,720
  int d = g & 127;
  int zz4 = g >> 7;                          // (b*LL + z0)/4
  int b = zz4 / (LL / 4);
  int r = zz4 - b * (LL / 4);
  int z0 = r * 4;
  int a = z0 >> 12, p = z0 & 4095;
  float w9[9];
  #pragma unroll
  for (int i = 0; i < 9; ++i) w9[i] = cw[d * 9 + i];
  float cbv = cb[d];
  float acc[4] = {cbv, cbv, cbv, cbv};
  #pragma unroll
  for (int di = 0; di < 3; ++di) {
    int aa = a + di - 1;
    if (aa < 0 || aa >= 5) continue;
    const float* rowb = X0 + ((size_t)b * LL + (size_t)aa * PIX) * 128 + d;
    #pragma unroll
    for (int dj = -1; dj <= 4; ++dj) {
      int pp = p + dj;
      if (pp < 0 || pp >= PIX) continue;
      float v = rowb[(size_t)pp * 128];
      #pragma unroll
      for (int o = 0; o < 4; ++o) {
        int rel = dj - o;
        if (rel >= -1 && rel <= 1) acc[o] = fmaf(w9[di * 3 + rel + 1], v, acc[o]);
      }
    }
  }
  float* dst = XT + (size_t)(zz4 * 4) * 128 + d;
  #pragma unroll
  for (int o = 0; o < 4; ++o) {
    float sg = 1.0f / (1.0f + __expf(-acc[o]));
    dst[(size_t)o * 128] = acc[o] * sg;
  }
}

// ---- x_proj GEMM (2 rows/thread), output permuted to scan order ----
__global__ __launch_bounds__(256, 4)
void k_gemmZ(const float* __restrict__ X, const float* __restrict__ W,
             float* __restrict__ ZdtB, float* __restrict__ ZC) {
  __shared__ float xl[64][129];
  __shared__ __align__(16) float wlT[32][164];
  int t = threadIdx.x;
  int row0 = blockIdx.x * 64;
  #pragma unroll
  for (int i = 0; i < 32; ++i) {
    int idx = i * 256 + t;
    xl[idx >> 7][idx & 127] = X[((size_t)row0 + (idx >> 7)) * 128 + (idx & 127)];
  }
  int zl2 = t & 31;          // rows 2*zl2, 2*zl2+1
  int mg  = t >> 5;          // 0..7: dir = mg>>1, col half = mg&1 (20 cols)
  float acc0[20], acc1[20];
  #pragma unroll
  for (int i = 0; i < 20; ++i) { acc0[i] = 0.0f; acc1[i] = 0.0f; }
  for (int c0 = 0; c0 < 128; c0 += 32) {
    __syncthreads();
    #pragma unroll
    for (int i = 0; i < 20; ++i) {
      int m = (t >> 5) * 20 + i;
      wlT[t & 31][m] = W[(size_t)m * 128 + c0 + (t & 31)];
    }
    __syncthreads();
    const float* xr0 = xl[2 * zl2];
    const float* xr1 = xl[2 * zl2 + 1];
    for (int cc = 0; cc < 32; ++cc) {
      float xv0 = xr0[c0 + cc];
      float xv1 = xr1[c0 + cc];
      const float4* wr = (const float4*)(&wlT[cc][mg * 20]);
      #pragma unroll
      for (int q = 0; q < 5; ++q) {
        float4 w4 = wr[q];
        acc0[q*4+0] = fmaf(w4.x, xv0, acc0[q*4+0]);
        acc0[q*4+1] = fmaf(w4.y, xv0, acc0[q*4+1]);
        acc0[q*4+2] = fmaf(w4.z, xv0, acc0[q*4+2]);
        acc0[q*4+3] = fmaf(w4.w, xv0, acc0[q*4+3]);
        acc1[q*4+0] = fmaf(w4.x, xv1, acc1[q*4+0]);
        acc1[q*4+1] = fmaf(w4.y, xv1, acc1[q*4+1]);
        acc1[q*4+2] = fmaf(w4.z, xv1, acc1[q*4+2]);
        acc1[q*4+3] = fmaf(w4.w, xv1, acc1[q*4+3]);
      }
    }
  }
  int dir = mg >> 1;
  int halfc = mg & 1;
  #pragma unroll
  for (int rr = 0; rr < 2; ++rr) {
    const float* acc = rr ? acc1 : acc0;
    int row = row0 + 2 * zl2 + rr;
    int b = row / LL, z = row - b * LL;
    int a = z >> 12, qq = z & 4095;
    int l;
    if (dir == 0)      l = z;
    else if (dir == 1) l = 5 * qq + a;
    else if (dir == 2) l = 20479 - z;
    else               l = 20479 - (5 * qq + a);
    size_t seqrow = (size_t)(b * 4 + dir) * LL + l;
    if (halfc == 0) {
      float* dD = ZdtB + seqrow * 24;
      #pragma unroll
      for (int q2 = 0; q2 < 5; ++q2)
        *(float4*)(dD + q2 * 4) = make_float4(acc[q2*4], acc[q2*4+1], acc[q2*4+2], acc[q2*4+3]);
    } else {
      float* dD = ZdtB + seqrow * 24;
      *(float4*)(dD + 20) = make_float4(acc[0], acc[1], acc[2], acc[3]);
      float* dC = ZC + seqrow * 16;
      #pragma unroll
      for (int q2 = 0; q2 < 4; ++q2)
        *(float4*)(dC + q2 * 4) = make_float4(acc[4+q2*4], acc[4+q2*4+1], acc[4+q2*4+2], acc[4+q2*4+3]);
    }
  }
}

// ------- single-pass chunked selective scan (per-wave, barrier-free) -------
// 128-thr blocks, x in regs, b128 LDS staging+reads, precomputed chain flag.
template<int K>
__device__ void scan_body(int b, int chunk, int dh, int lane,
    const float* __restrict__ XT, const float* __restrict__ ZdtB,
    const float* __restrict__ ZC,
    const float* __restrict__ dt_w, const float* __restrict__ dt_b,
    const float* __restrict__ A_logs, const float* __restrict__ Ds,
    const int* __restrict__ chainflags,
    float* __restrict__ h_out, float* __restrict__ sumdts,
    float* __restrict__ ysz, float* __restrict__ cumqv,
    float* stD, float* stC)
{
  const int d = dh * 64 + lane;
  const int kd = K * 128 + d;
  bool chainok = chainflags[kd] != 0;
  float dw[8];
  #pragma unroll
  for (int r = 0; r < 8; ++r) dw[r] = dt_w[(size_t)kd * 8 + r];
  const float dtb = dt_b[kd], dsv = Ds[kd];
  v2f h2[8];
  #pragma unroll
  for (int n = 0; n < 8; ++n) h2[n] = (v2f){0.0f, 0.0f};
  float sdt = 0.0f;
  float qrun = 1.0f;
  const int seq = b * 4 + K;
  const float* ZDs = ZdtB + (size_t)seq * LL * 24;
  const float* ZCs = ZC + (size_t)seq * LL * 16;
  const float* Xb = XT + (size_t)b * LL * 128;
  float* ysb = ysz + (size_t)seq * PIX * 128;
  float* cqb = cumqv + (size_t)seq * PIX * 128;
  const int l0 = chunk * LC;

  if (__all(chainok ? 1 : 0)) {
    #pragma unroll 1
    for (int sub = 0; sub < NSUB; ++sub) {
      const int ls = l0 + sub * SUBS;
      // stage dt/B rows (SUBS*24=240 floats = 60 float4) via per-wave LDS
      {
        const v4f* srcD = (const v4f*)(ZDs + (size_t)ls * 24);
        if (lane < SUBS * 6) ((v4f*)stD)[lane] = srcD[lane];
      }
      int s0c = 0;
      bool needC;
      if (K == 0)      needC = (ls < PIX);
      else if (K == 2) needC = (ls + SUBS > LL - PIX);
      else             needC = true;
      if (K == 1) s0c = (5 - (ls % 5)) % 5;
      if (K == 3) s0c = (9 - (ls % 5)) % 5;
      if (needC) {
        if (K == 0 || K == 2) {
          const v4f* srcC = (const v4f*)(ZCs + (size_t)ls * 16);
          if (lane < SUBS * 4) ((v4f*)stC)[lane] = srcC[lane];
        } else {
          if (lane < 8) {
            int l = ls + s0c + 5 * (lane >> 2);
            if (l > LL - 1) l = LL - 1;
            ((v4f*)stC)[lane] = *(const v4f*)(ZCs + (size_t)l * 16 + (lane & 3) * 4);
          }
        }
      }
      // register-stage x for SUBS steps (per-lane, compile-time indexed)
      float xr[SUBS];
      #pragma unroll
      for (int s = 0; s < SUBS; ++s) {
        int z = zmapT<K>(ls + s);
        xr[s] = Xb[(size_t)z * 128 + d];
      }
      int zc = 0;
      if (K == 1) zc = (ls + s0c) / 5;
      if (K == 3) zc = (20479 - ls - s0c) / 5;
      int yj = 0;
      #pragma unroll
      for (int s = 0; s < SUBS; ++s) {
        const v4f* rowD4 = (const v4f*)(stD + s * 24);
        v4f rA = rowD4[0], rB = rowD4[1];
        float dtl = dtb;
        dtl = fmaf(dw[0], rA[0], dtl); dtl = fmaf(dw[1], rA[1], dtl);
        dtl = fmaf(dw[2], rA[2], dtl); dtl = fmaf(dw[3], rA[3], dtl);
        dtl = fmaf(dw[4], rB[0], dtl); dtl = fmaf(dw[5], rB[1], dtl);
        dtl = fmaf(dw[6], rB[2], dtl); dtl = fmaf(dw[7], rB[3], dtl);
        float edt = __expf(dtl);
        float e1 = __builtin_amdgcn_rcpf(1.0f + edt);  // exp(-softplus(dtl))
        float dt = (dtl > 20.0f) ? dtl : __logf(1.0f + edt);
        sdt += dt;
        qrun *= e1;
        float xsv = xr[s];
        float dtx = dt * xsv;
        v2f dtx2 = {dtx, dtx};
        float e2 = e1 * e1;
        v2f E[8];
        E[0] = (v2f){e1, e2};
        v2f e2s = {e2, e2};
        E[1] = pk_mul(E[0], e2s);   // e3,e4
        E[2] = pk_mul(E[1], e2s);   // e5,e6
        E[3] = pk_mul(E[2], e2s);   // e7,e8
        float e8 = E[3][1];
        v2f e8s = {e8, e8};
        E[4] = pk_mul(E[0], e8s);
        E[5] = pk_mul(E[1], e8s);
        E[6] = pk_mul(E[2], e8s);
        E[7] = pk_mul(E[3], e8s);
        v4f B0 = rowD4[2], B1 = rowD4[3], B2v = rowD4[4], B3 = rowD4[5];
        v2f m;
        m = pk_mul(dtx2, (v2f){B0[0], B0[1]});  PK_DECAY(h2[0], E[0], m);
        m = pk_mul(dtx2, (v2f){B0[2], B0[3]});  PK_DECAY(h2[1], E[1], m);
        m = pk_mul(dtx2, (v2f){B1[0], B1[1]});  PK_DECAY(h2[2], E[2], m);
        m = pk_mul(dtx2, (v2f){B1[2], B1[3]});  PK_DECAY(h2[3], E[3], m);
        m = pk_mul(dtx2, (v2f){B2v[0], B2v[1]}); PK_DECAY(h2[4], E[4], m);
        m = pk_mul(dtx2, (v2f){B2v[2], B2v[3]}); PK_DECAY(h2[5], E[5], m);
        m = pk_mul(dtx2, (v2f){B3[0], B3[1]});  PK_DECAY(h2[6], E[6], m);
        m = pk_mul(dtx2, (v2f){B3[2], B3[3]});  PK_DECAY(h2[7], E[7], m);
        bool doY;
        int z;
        if (K == 0)      { z = ls + s;            doY = (z < PIX); }
        else if (K == 2) { z = 20479 - (ls + s);  doY = (z < PIX); }
        else             { z = zc;                doY = ((s % 5) == s0c); }
        if (doY) {
          const v4f* C4 = (const v4f*)(stC + ((K == 0 || K == 2) ? s : yj) * 16);
          v4f C0 = C4[0], C1 = C4[1], C2v = C4[2], C3 = C4[3];
          v2f ya = pk_mul(h2[0], (v2f){C0[0], C0[1]});
          PK_FMA_ACC(ya, h2[1], ((v2f){C0[2], C0[3]}));
          PK_FMA_ACC(ya, h2[2], ((v2f){C1[0], C1[1]}));
          PK_FMA_ACC(ya, h2[3], ((v2f){C1[2], C1[3]}));
          PK_FMA_ACC(ya, h2[4], ((v2f){C2v[0], C2v[1]}));
          PK_FMA_ACC(ya, h2[5], ((v2f){C2v[2], C2v[3]}));
          PK_FMA_ACC(ya, h2[6], ((v2f){C3[0], C3[1]}));
          PK_FMA_ACC(ya, h2[7], ((v2f){C3[2], C3[3]}));
          float y = fmaf(dsv, xsv, ya[0] + ya[1]);
          size_t o = (size_t)z * 128 + d;
          ysb[o] = y;
          cqb[o] = qrun;
          ++yj;
          if (K == 1) ++zc;
          if (K == 3) --zc;
        }
      }
    }
  } else {
    // general fallback (compact, never taken for this A_logs)
    float An[NS];
    #pragma unroll
    for (int n = 0; n < NS; ++n) An[n] = -__expf(A_logs[(size_t)kd * 16 + n]);
    float hs[NS];
    #pragma unroll
    for (int n = 0; n < NS; ++n) hs[n] = 0.0f;
    #pragma unroll 1
    for (int l = l0; l < l0 + LC; ++l) {
      int z = zmapT<K>(l);
      const float* rowD = ZDs + (size_t)l * 24;
      float dtl = dtb;
      #pragma unroll
      for (int r = 0; r < RR; ++r) dtl += dw[r] * rowD[r];
      float edt = __expf(dtl);
      float dt = (dtl > 20.0f) ? dtl : __logf(1.0f + edt);
      sdt += dt;
      float xv = Xb[(size_t)z * 128 + d];
      float dtx = dt * xv;
      #pragma unroll
      for (int n = 0; n < NS; ++n)
        hs[n] = hs[n] * __expf(dt * An[n]) + dtx * rowD[8 + n];
      if (z < PIX) {
        const float* rowC = ZCs + (size_t)l * 16;
        float y = dsv * xv;
        #pragma unroll
        for (int n = 0; n < NS; ++n) y = fmaf(hs[n], rowC[n], y);
        size_t o = (size_t)z * 128 + d;
        ysb[o] = y;
        cqb[o] = __expf(-sdt);
      }
    }
    #pragma unroll
    for (int n = 0; n < 8; ++n) h2[n] = (v2f){hs[2*n], hs[2*n+1]};
  }
  float* ho = h_out + (((size_t)seq * NCHK + chunk) * 128 + d) * 16;
  #pragma unroll
  for (int n = 0; n < 8; ++n) {
    ho[2*n] = h2[n][0];
    ho[2*n+1] = h2[n][1];
  }
  sumdts[((size_t)seq * NCHK + chunk) * 128 + d] = sdt;
}

__global__ __launch_bounds__(128, 8)
void k_scan1(const float* __restrict__ XT, const float* __restrict__ ZdtB,
             const float* __restrict__ ZC,
             const float* __restrict__ dt_w, const float* __restrict__ dt_b,
             const float* __restrict__ A_logs, const float* __restrict__ Ds,
             const int* __restrict__ chainflags,
             float* __restrict__ h_out, float* __restrict__ sumdts,
             float* __restrict__ ysz, float* __restrict__ cumqv) {
  __shared__ __align__(16) float stD_all[2][SUBS * 24];
  __shared__ __align__(16) float stC_all[2][SUBS * 16];
  int tid = threadIdx.x, wid = tid >> 6, lane = tid & 63;
  int bid = blockIdx.x;            // B * (K0CH + 3*512) = 3280
  int bb = bid / (K0CH + 3 * NCHK);
  int idx = bid - bb * (K0CH + 3 * NCHK);
  int k, chunk;
  if (idx < K0CH)                 { k = 0; chunk = idx; }
  else if (idx < K0CH + NCHK)     { k = 1; chunk = idx - K0CH; }
  else if (idx < K0CH + 2 * NCHK) { k = 2; chunk = idx - (K0CH + NCHK); }
  else                            { k = 3; chunk = idx - (K0CH + 2 * NCHK); }
  int dh = wid;
  float* stD = stD_all[wid];
  float* stC = stC_all[wid];
  switch (k) {
    case 0: scan_body<0>(bb, chunk, dh, lane, XT, ZdtB, ZC, dt_w, dt_b, A_logs, Ds, chainflags, h_out, sumdts, ysz, cumqv, stD, stC); break;
    case 1: scan_body<1>(bb, chunk, dh, lane, XT, ZdtB, ZC, dt_w, dt_b, A_logs, Ds, chainflags, h_out, sumdts, ysz, cumqv, stD, stC); break;
    case 2: scan_body<2>(bb, chunk, dh, lane, XT, ZdtB, ZC, dt_w, dt_b, A_logs, Ds, chainflags, h_out, sumdts, ysz, cumqv, stD, stC); break;
    default: scan_body<3>(bb, chunk, dh, lane, XT, ZdtB, ZC, dt_w, dt_b, A_logs, Ds, chainflags, h_out, sumdts, ysz, cumqv, stD, stC); break;
  }
}

// ---- combine level A: per-group affine fold (Ag = prod a, Bg = fold b) ----
// k=0 only needs groups 0..6 (output chunks <=102).
__global__ __launch_bounds__(256)
void k_comb_a(const float* __restrict__ A_logs, const float* __restrict__ sumdts,
              const float* __restrict__ h_out, float* __restrict__ Ag,
              float* __restrict__ Bg) {
  int g = blockIdx.x * 256 + threadIdx.x;   // 8*32*128*16 = 524288
  int n = g & 15;
  int d = (g >> 4) & 127;
  int grp = (g >> 11) & 31;
  int seq = g >> 16;
  int k = seq & 3;
  if (k == 0 && grp > 6) return;            // unused by prefix/replay
  float An = -__expf(A_logs[(size_t)(k * 128 + d) * 16 + n]);
  float A = 1.0f, Bv = 0.0f;
  size_t cbase = (size_t)seq * NCHK + grp * GCH;
  #pragma unroll 4
  for (int j = 0; j < GCH; ++j) {
    float a = __expf(An * sumdts[(cbase + j) * 128 + d]);
    float b = h_out[((cbase + j) * 128 + d) * 16 + n];
    A *= a;
    Bv = Bv * a + b;
  }
  size_t o = (((size_t)seq * NGRP + grp) * 128 + d) * 16 + n;
  Ag[o] = A;
  Bg[o] = Bv;
}

// ---- combine level B: prefix over 32 groups ----
__global__ __launch_bounds__(256)
void k_comb_b(const float* __restrict__ Ag, const float* __restrict__ Bg,
              float* __restrict__ Hg) {
  int g = blockIdx.x * 256 + threadIdx.x;   // 8*128*16 = 16384
  int n = g & 15;
  int d = (g >> 4) & 127;
  int seq = g >> 11;
  float H = 0.0f;
  #pragma unroll
  for (int grp = 0; grp < NGRP; ++grp) {
    size_t o = (((size_t)seq * NGRP + grp) * 128 + d) * 16 + n;
    Hg[o] = H;
    H = Ag[o] * H + Bg[o];
  }
}

// ---- combine level C: replay within group -> h_in per chunk ----
// k=0 needs groups 0..6 only; k=2 replay needs groups 25..31 only.
__global__ __launch_bounds__(256)
void k_comb_c(const float* __restrict__ A_logs, const float* __restrict__ sumdts,
              const float* __restrict__ h_out, const float* __restrict__ Hg,
              float* __restrict__ h_in) {
  int g = blockIdx.x * 256 + threadIdx.x;   // 524288
  int n = g & 15;
  int d = (g >> 4) & 127;
  int grp = (g >> 11) & 31;
  int seq = g >> 16;
  int k = seq & 3;
  if (k == 0 && grp > 6) return;
  if (k == 2 && grp < 25) return;
  float An = -__expf(A_logs[(size_t)(k * 128 + d) * 16 + n]);
  float h = Hg[(((size_t)seq * NGRP + grp) * 128 + d) * 16 + n];
  size_t cbase = (size_t)seq * NCHK + grp * GCH;
  #pragma unroll 4
  for (int j = 0; j < GCH; ++j) {
    size_t o = ((cbase + j) * 128 + d) * 16 + n;
    h_in[o] = h;
    float a = __expf(An * sumdts[(cbase + j) * 128 + d]);
    h = a * h + h_out[o];
  }
}

// ------- transpose out_proj_w + precompute per-kd chain flags -------
__global__ __launch_bounds__(256)
void k_wt(const float* __restrict__ Wo, float* __restrict__ WT,
          const float* __restrict__ A_logs, int* __restrict__ chainflags) {
  if (blockIdx.x >= 16) {
    int kd = (blockIdx.x - 16) * 256 + threadIdx.x;   // 0..511
    bool c = true;
    #pragma unroll
    for (int n = 0; n < NS; ++n) {
      float An = -__expf(A_logs[(size_t)kd * 16 + n]);
      c = c && (fabsf(An + (float)(n + 1)) < 3e-5f * (float)(n + 1));
    }
    chainflags[kd] = c ? 1 : 0;
    return;
  }
  __shared__ float tl[32][33];
  int bx = blockIdx.x & 3, by = blockIdx.x >> 2;
  int t = threadIdx.x;
  int tx = t & 31, ty = t >> 5;
  #pragma unroll
  for (int i = 0; i < 4; ++i)
    tl[ty + i * 8][tx] = Wo[(size_t)(by * 32 + ty + i * 8) * 128 + bx * 32 + tx];
  __syncthreads();
  #pragma unroll
  for (int i = 0; i < 4; ++i)
    WT[(size_t)(bx * 32 + ty + i * 8) * 128 + by * 32 + tx] = tl[tx][ty + i * 8];
}

// ------- merge 4 dirs + cross-chunk fix + LayerNorm + out_proj -------
__global__ __launch_bounds__(256)
void k_merge(const float* __restrict__ ysz, const float* __restrict__ ZC,
             const float* __restrict__ A_logs, const float* __restrict__ h_in,
             const float* __restrict__ cumq, const int* __restrict__ chainflags,
             const float* __restrict__ ln_g, const float* __restrict__ ln_b,
             const float* __restrict__ WT, float* __restrict__ out) {
  __shared__ __align__(16) float ynT[128][20];
  __shared__ float red[4][8][2];
  int blk = blockIdx.x;          // 512: b = blk>>8, ptile = blk&255
  int b = blk >> 8;
  int p0 = (blk & 255) * 16;
  int tid = threadIdx.x;
  int t = tid & 127;             // channel d
  int half = tid >> 7;           // 0/1
  int w = tid >> 6;              // wave 0..3
  float g = ln_g[t], bb = ln_b[t];
  bool cok[4];
  #pragma unroll
  for (int k = 0; k < 4; ++k) cok[k] = chainflags[k * 128 + t] != 0;
  float yv[8];
  #pragma unroll
  for (int i = 0; i < 8; ++i) {
    int p = p0 + 2 * i + half;
    float y = 0.0f;
    #pragma unroll
    for (int k = 0; k < 4; ++k) {
      size_t zi = ((size_t)(b * 4 + k) * PIX + p) * 128 + t;
      float yk = ysz[zi];
      int l;
      if (k == 0)      l = p;
      else if (k == 1) l = 5 * p;
      else if (k == 2) l = 20479 - p;
      else             l = 20479 - 5 * p;
      int chunk = l / LC;
      float q = cumq[zi];
      const v2f* hi2 = (const v2f*)(h_in + (((size_t)(b * 4 + k) * NCHK + chunk) * 128 + t) * 16);
      const v2f* Cr2 = (const v2f*)(ZC + ((size_t)(b * 4 + k) * LL + l) * 16);
      float fix;
      if (cok[k]) {
        float q2 = q * q;
        v2f Q[8];
        Q[0] = (v2f){q, q2};
        v2f q2s = {q2, q2};
        Q[1] = pk_mul(Q[0], q2s);
        Q[2] = pk_mul(Q[1], q2s);
        Q[3] = pk_mul(Q[2], q2s);
        float q8 = Q[3][1];
        v2f q8s = {q8, q8};
        Q[4] = pk_mul(Q[0], q8s);
        Q[5] = pk_mul(Q[1], q8s);
        Q[6] = pk_mul(Q[2], q8s);
        Q[7] = pk_mul(Q[3], q8s);
        v2f a = pk_mul(pk_mul(hi2[0], Cr2[0]), Q[0]);
        #pragma unroll
        for (int j = 1; j < 8; ++j) {
          v2f m = pk_mul(hi2[j], Cr2[j]);
          PK_FMA_ACC(a, m, Q[j]);
        }
        fix = a[0] + a[1];
      } else {
        float cd = -__logf(q);
        fix = 0.0f;
        const float* hi = (const float*)hi2;
        const float* Cr = (const float*)Cr2;
        #pragma unroll
        for (int n = 0; n < NS; ++n) {
          float An = -__expf(A_logs[(size_t)(k * 128 + t) * 16 + n]);
          fix += Cr[n] * hi[n] * __expf(An * cd);
        }
      }
      y += yk + fix;
    }
    yv[i] = y;
    float s1 = y, s2 = y * y;
    #pragma unroll
    for (int off = 32; off; off >>= 1) {
      s1 += __shfl_xor(s1, off);
      s2 += __shfl_xor(s2, off);
    }
    if ((tid & 63) == 0) { red[w][i][0] = s1; red[w][i][1] = s2; }
  }
  __syncthreads();
  #pragma unroll
  for (int i = 0; i < 8; ++i) {
    int pl = 2 * i + half;
    float S1 = red[half * 2][i][0] + red[half * 2 + 1][i][0];
    float S2 = red[half * 2][i][1] + red[half * 2 + 1][i][1];
    float mu = S1 * (1.0f / 128.0f);
    float var = S2 * (1.0f / 128.0f) - mu * mu;
    float rs = rsqrtf(var + 1e-5f);
    ynT[t][pl] = (yv[i] - mu) * rs * g + bb;
  }
  __syncthreads();
  float acc[8];
  #pragma unroll
  for (int i = 0; i < 8; ++i) acc[i] = 0.0f;
  for (int dd = 0; dd < 128; ++dd) {
    float wv = WT[(size_t)dd * 128 + t];
    const float4* yr = (const float4*)(&ynT[dd][half * 8]);
    float4 ya = yr[0], yb4 = yr[1];
    acc[0] = fmaf(ya.x,  wv, acc[0]);
    acc[1] = fmaf(ya.y,  wv, acc[1]);
    acc[2] = fmaf(ya.z,  wv, acc[2]);
    acc[3] = fmaf(ya.w,  wv, acc[3]);
    acc[4] = fmaf(yb4.x, wv, acc[4]);
    acc[5] = fmaf(yb4.y, wv, acc[5]);
    acc[6] = fmaf(yb4.z, wv, acc[6]);
    acc[7] = fmaf(yb4.w, wv, acc[7]);
  }
  float* dst = out + ((size_t)b * 128 + t) * PIX + p0 + half * 8;
  *(float4*)(dst)     = make_float4(acc[0], acc[1], acc[2], acc[3]);
  *(float4*)(dst + 4) = make_float4(acc[4], acc[5], acc[6], acc[7]);
}

extern "C" void kernel_launch(void* const* d_in, const int* in_sizes, int n_in,
                              void* d_out, int out_size, void* d_ws, size_t ws_size,
                              hipStream_t stream) {
  const float* x         = (const float*)d_in[0];
  // d_in[1] record_len unused
  const float* nam       = (const float*)d_in[2];
  const float* in_proj_w = (const float*)d_in[3];
  const float* conv_w    = (const float*)d_in[4];
  const float* conv_b    = (const float*)d_in[5];
  const float* x_proj_w  = (const float*)d_in[6];
  const float* dt_w      = (const float*)d_in[7];
  const float* dt_b      = (const float*)d_in[8];
  const float* A_logs    = (const float*)d_in[9];
  const float* Ds        = (const float*)d_in[10];
  const float* ln_g      = (const float*)d_in[11];
  const float* ln_b      = (const float*)d_in[12];
  const float* out_proj_w= (const float*)d_in[13];
  float* out = (float*)d_out;
  float* ws  = (float*)d_ws;

  // workspace layout (floats), total ~32.8M (~131 MB)
  float* warped = ws;                          // 5,242,880
  float* alpha  = warped + 5242880;            //    40,960
  float* X0     = alpha  + 40960;              // 5,242,880   (end 10,526,720)
  float* XT     = X0     + 5242880;            // 5,242,880
  float* ZdtB   = XT     + 5242880;            // 3,932,160   (end 19,701,760)
  float* ZC     = ZdtB   + 3932160;            // 2,621,440
  float* sums   = ZC     + 2621440;            //   524,288
  float* ysz    = sums   + 524288;             // 4,194,304
  float* cumq   = ysz    + 4194304;            // 4,194,304
  float* WT     = cumq   + 4194304;            //    16,384
  float* Ag     = WT     + 16384;              //   524,288
  float* Bg     = Ag     + 524288;             //   524,288
  float* Hg     = Bg     + 524288;             //   524,288
  int*   chainflags = (int*)(Hg + 524288);     //       512 ints

  // aliases: h_out (8.39M) over warped+alpha+X0 (dead after k_conv);
  //          h_in  (8.39M) over XT+ZdtB (dead after k_scan1)
  float* h_out = ws;
  float* h_in  = XT;

  k_wt     <<<18,    256, 0, stream>>>(out_proj_w, WT, A_logs, chainflags);
  k_warp   <<<20480, 256, 0, stream>>>(x, nam, warped);
  k_alpha  <<<128,   512, 0, stream>>>(warped, nam, alpha);
  k_gemm_in<<<640,   256, 0, stream>>>(warped, alpha, in_proj_w, X0);
  k_conv   <<<5120,  256, 0, stream>>>(X0, conv_w, conv_b, XT);
  k_gemmZ  <<<640,   256, 0, stream>>>(XT, x_proj_w, ZdtB, ZC);
  k_scan1  <<<B_S * (K0CH + 3 * NCHK), 128, 0, stream>>>(XT, ZdtB, ZC, dt_w, dt_b,
                                                         A_logs, Ds, chainflags,
                                                         h_out, sums, ysz, cumq);
  k_comb_a <<<2048,  256, 0, stream>>>(A_logs, sums, h_out, Ag, Bg);
  k_comb_b <<<64,    256, 0, stream>>>(Ag, Bg, Hg);
  k_comb_c <<<2048,  256, 0, stream>>>(A_logs, sums, h_out, Hg, h_in);
  k_merge  <<<512,   256, 0, stream>>>(ysz, ZC, A_logs, h_in, cumq, chainflags,
                                       ln_g, ln_b, WT, out);
}